// Round 5
// baseline (384.478 us; speedup 1.0000x reference)
//
#include <hip/hip_runtime.h>
#include <hip/hip_bf16.h>

constexpr int B  = 2;
constexpr int S  = 2048;
constexpr int D  = 1024;
constexpr int H  = 16;

typedef unsigned short u16t;
typedef unsigned long long u64;
typedef __attribute__((ext_vector_type(8))) short short8;
typedef __attribute__((ext_vector_type(4))) float float4v;

__device__ __forceinline__ float b2f(u16t u) {
    union { unsigned int i; float f; } c; c.i = ((unsigned int)u) << 16; return c.f;
}
__device__ __forceinline__ u16t f2b(float f) {
    __hip_bfloat16 h = __float2bfloat16(f);
    union { __hip_bfloat16 h; u16t u; } c; c.h = h; return c.u;
}
__device__ __forceinline__ u64 pack4(float4 v) {
    return (u64)f2b(v.x) | ((u64)f2b(v.y) << 16) | ((u64)f2b(v.z) << 32) | ((u64)f2b(v.w) << 48);
}

// ws layout (u16 units)
constexpr size_t XB_OFF = 0;          // x bf16       4194304
constexpr size_t WQ_OFF = 4194304;    // Wq bf16      1048576
constexpr size_t WK_OFF = 5242880;
constexpr size_t WV_OFF = 6291456;
constexpr size_t ER_OFF = 7340032;    // Er bf16       131072
constexpr size_t QW_OFF = 7471104;    // q  bf16 [bh][s][d]
constexpr size_t KW_OFF = 11665408;   // k  bf16 [bh][s][d]
constexpr size_t VT_OFF = 15859712;   // v^T bf16 [bh][d][s]

// ---------------------------------------------------------------------------
// Prep: convert x, Wq, Wk, Wv, Er fp32 -> bf16 into one contiguous ws region.
// ---------------------------------------------------------------------------
__global__ __launch_bounds__(256) void prep_bf16(
    const float* __restrict__ x,  const float* __restrict__ Wq,
    const float* __restrict__ Wk, const float* __restrict__ Wv,
    const float* __restrict__ Er, u64* __restrict__ dst)
{
    size_t i4 = (size_t)blockIdx.x * 256 + threadIdx.x;   // float4 index
    const float* src; size_t off;
    if      (i4 < 1048576) { src = x;  off = i4; }
    else if (i4 < 1310720) { src = Wq; off = i4 - 1048576; }
    else if (i4 < 1572864) { src = Wk; off = i4 - 1310720; }
    else if (i4 < 1835008) { src = Wv; off = i4 - 1572864; }
    else                   { src = Er; off = i4 - 1835008; }
    float4 v = ((const float4*)src)[off];
    dst[i4] = pack4(v);
}

// ---------------------------------------------------------------------------
// QKV projection, bf16 MFMA, BM=BN=128, BK=64.
// q,k -> [bh][s][d] bf16; v -> transposed [bh][d][s] bf16.
// FIX (round 5): staging loads/stores are short8 (16 B = 8 bf16), matching the
// c*8 element stride. Round 3/4 used u64 (4 bf16) -> half of every tile was
// uninitialized LDS -> garbage/NaN q,k,v. This was the round-3/4 failure.
// ---------------------------------------------------------------------------
__global__ __launch_bounds__(256, 3) void qkv_mfma(
    const u16t* __restrict__ xb,
    const u16t* __restrict__ wqb, const u16t* __restrict__ wkb, const u16t* __restrict__ wvb,
    const float* __restrict__ bq, const float* __restrict__ bk, const float* __restrict__ bv,
    u16t* __restrict__ qo, u16t* __restrict__ ko, u16t* __restrict__ vT)
{
    const int z = blockIdx.z;
    const u16t*  W    = (z == 0) ? wqb : (z == 1) ? wkb : wvb;
    const float* bias = (z == 0) ? bq  : (z == 1) ? bk  : bv;

    __shared__ __align__(16) u16t Xs[128][72];
    __shared__ __align__(16) u16t Ws[128][72];

    const int tid = threadIdx.x;
    const int w = tid >> 6, lane = tid & 63;
    const int quad = lane >> 4, l16 = lane & 15;
    const int m0 = blockIdx.x * 128, n0 = blockIdx.y * 128;
    const int mi = (w >> 1) * 64, ni = (w & 1) * 64;

    float4v acc[4][4];
    #pragma unroll
    for (int mt = 0; mt < 4; ++mt)
        #pragma unroll
        for (int nt = 0; nt < 4; ++nt) acc[mt][nt] = (float4v){0.f, 0.f, 0.f, 0.f};

    for (int k0 = 0; k0 < D; k0 += 64) {
        short8 xa[4], wa[4];
        #pragma unroll
        for (int it = 0; it < 4; ++it) {
            int idx = tid + it * 256, r = idx >> 3, c = idx & 7;
            xa[it] = *(const short8*)&xb[(size_t)(m0 + r) * D + k0 + c * 8];
            wa[it] = *(const short8*)&W [(size_t)(n0 + r) * D + k0 + c * 8];
        }
        __syncthreads();
        #pragma unroll
        for (int it = 0; it < 4; ++it) {
            int idx = tid + it * 256, r = idx >> 3, c = idx & 7;
            *(short8*)&Xs[r][c * 8] = xa[it];
            *(short8*)&Ws[r][c * 8] = wa[it];
        }
        __syncthreads();
        short8 af[4][2], bf[4][2];
        #pragma unroll
        for (int mt = 0; mt < 4; ++mt) {
            af[mt][0] = *(const short8*)&Xs[mi + mt * 16 + l16][quad * 8];
            af[mt][1] = *(const short8*)&Xs[mi + mt * 16 + l16][quad * 8 + 32];
        }
        #pragma unroll
        for (int nt = 0; nt < 4; ++nt) {
            bf[nt][0] = *(const short8*)&Ws[ni + nt * 16 + l16][quad * 8];
            bf[nt][1] = *(const short8*)&Ws[ni + nt * 16 + l16][quad * 8 + 32];
        }
        #pragma unroll
        for (int mt = 0; mt < 4; ++mt)
            #pragma unroll
            for (int nt = 0; nt < 4; ++nt) {
                acc[mt][nt] = __builtin_amdgcn_mfma_f32_16x16x32_bf16(af[mt][0], bf[nt][0], acc[mt][nt], 0, 0, 0);
                acc[mt][nt] = __builtin_amdgcn_mfma_f32_16x16x32_bf16(af[mt][1], bf[nt][1], acc[mt][nt], 0, 0, 0);
            }
    }

    float bias_v[4];
    #pragma unroll
    for (int nt = 0; nt < 4; ++nt) bias_v[nt] = bias[n0 + ni + nt * 16 + l16];

    #pragma unroll
    for (int mt = 0; mt < 4; ++mt)
        #pragma unroll
        for (int nt = 0; nt < 4; ++nt) {
            int n = n0 + ni + nt * 16 + l16;
            int h = n >> 6, dh = n & 63;
            int mb = m0 + mi + mt * 16 + quad * 4;
            int b_ = mb >> 11, s = mb & (S - 1);
            if (z == 2) {
                float4 o;
                o.x = acc[mt][nt][0] + bias_v[nt];
                o.y = acc[mt][nt][1] + bias_v[nt];
                o.z = acc[mt][nt][2] + bias_v[nt];
                o.w = acc[mt][nt][3] + bias_v[nt];
                *(u64*)&vT[((size_t)(b_ * H + h) * 64 + dh) * S + s] = pack4(o);
            } else {
                u16t* out = (z == 0) ? qo : ko;
                #pragma unroll
                for (int rg = 0; rg < 4; ++rg)
                    out[((size_t)(b_ * H + h) * S + s + rg) * 64 + dh] =
                        f2b(acc[mt][nt][rg] + bias_v[nt]);
            }
        }
}

// ---------------------------------------------------------------------------
// Flash attention + relative position, bf16 MFMA, bpermute Srel extraction.
// Staging via explicit vector load + swizzled ds_write.
// LDS: Ks 8K + Vs 8K + ErW 16K + Ps 8K = 40 KB.
// ---------------------------------------------------------------------------
__global__ __launch_bounds__(256, 3) void attn_mfma(
    const u16t* __restrict__ q, const u16t* __restrict__ k,
    const u16t* __restrict__ vT, const u16t* __restrict__ er,
    float* __restrict__ out)
{
    __shared__ __align__(16) u16t KsS[64 * 64];
    __shared__ __align__(16) u16t VsS[64 * 64];
    __shared__ __align__(16) u16t ErS[128 * 64];
    __shared__ __align__(16) u16t PsS[64 * 64];
    char* KsB = (char*)KsS;
    char* VsB = (char*)VsS;
    char* ErB = (char*)ErS;
    char* PsB = (char*)PsS;

    const int tid = threadIdx.x;
    const int w = tid >> 6, lane = tid & 63;
    const int quad = lane >> 4, l16 = lane & 15;
    const int bh = blockIdx.x;
    const int ix = (int)gridDim.y - 1 - (int)blockIdx.y;   // longest blocks dispatch first
    const int s0 = ix * 64;
    const int hh = bh & (H - 1), bb = bh >> 4;

    const u16t* qb = q  + (size_t)bh * S * 64;
    const u16t* kb = k  + (size_t)bh * S * 64;
    const u16t* vb = vT + (size_t)bh * 64 * S;

    // Q A-fragments, registers forever
    const size_t qoff = (size_t)(s0 + w * 16 + l16) * 64;
    const short8 Qa0 = *(const short8*)&qb[qoff + quad * 8];
    const short8 Qa1 = *(const short8*)&qb[qoff + 32 + quad * 8];

    float4v accO[4], L[5];
    #pragma unroll
    for (int t = 0; t < 4; ++t) accO[t] = (float4v){0.f, 0.f, 0.f, 0.f};
    float mrow[4] = {-1e30f, -1e30f, -1e30f, -1e30f};
    float lrow[4] = {0.f, 0.f, 0.f, 0.f};

    const int xk = (l16 & 7);   // swizzle key for frag reads (row & 7 == l16 & 7)

#define COMP_L(c) { \
        int prow_ = (((3 - w + (c)) * 16 + l16) ^ flip); \
        short8 b0_ = *(const short8*)(ErB + prow_ * 128 + ((quad ^ xk) << 4)); \
        short8 b1_ = *(const short8*)(ErB + prow_ * 128 + (((quad + 4) ^ xk) << 4)); \
        float4v e_ = (float4v){0.f, 0.f, 0.f, 0.f}; \
        e_ = __builtin_amdgcn_mfma_f32_16x16x32_bf16(Qa0, b0_, e_, 0, 0, 0); \
        e_ = __builtin_amdgcn_mfma_f32_16x16x32_bf16(Qa1, b1_, e_, 0, 0, 0); \
        L[c] = e_; }

    for (int jt = 0; jt <= ix; ++jt) {
        const int t0 = jt * 64;
        const int jbase = S - 64 - s0 + t0;   // >= 0
        const int flip = (jt & 1) * 64;

        // ---- global loads into registers (no LDS touch yet) ----
        short8 kreg[2], vreg[2], ereg[4];
        int   kpos[2], vpos[2], epos[4];
        int   n_er;
        #pragma unroll
        for (int it = 0; it < 2; ++it) {
            int idx = tid + it * 256;            // [0,512)
            int r = idx >> 3, c = idx & 7;
            kreg[it] = *(const short8*)&kb[(size_t)(t0 + r) * 64 + c * 8];
            kpos[it] = r * 128 + ((c ^ (r & 7)) << 4);
            vreg[it] = *(const short8*)&vb[(size_t)r * S + t0 + c * 8];
            vpos[it] = kpos[it];
        }
        if (jt == 0) {
            n_er = 4;
            #pragma unroll
            for (int it = 0; it < 4; ++it) {
                int idx = tid + it * 256;        // [0,1024)
                int r = idx >> 3, c = idx & 7;   // r in [0,128)
                int grow = jbase + r; if (grow > S - 1) grow = S - 1;
                ereg[it] = *(const short8*)&er[(size_t)grow * 64 + c * 8];
                epos[it] = r * 128 + ((c ^ (r & 7)) << 4);
            }
        } else {
            n_er = 2;
            int sb = (jt & 1) ? 0 : 64;
            #pragma unroll
            for (int it = 0; it < 2; ++it) {
                int idx = tid + it * 256;        // [0,512)
                int r = idx >> 3, c = idx & 7;   // r in [0,64)
                int pr = sb + r;                 // physical row; pr&7 == r&7
                int grow = jbase + 64 + r; if (grow > S - 1) grow = S - 1;
                ereg[it] = *(const short8*)&er[(size_t)grow * 64 + c * 8];
                epos[it] = pr * 128 + ((c ^ (r & 7)) << 4);
            }
        }

        __syncthreads();   // all reads of Ks/Vs/ErW from prev iter done

        #pragma unroll
        for (int it = 0; it < 2; ++it) {
            *(short8*)(KsB + kpos[it]) = kreg[it];
            *(short8*)(VsB + vpos[it]) = vreg[it];
        }
        for (int it = 0; it < n_er; ++it)
            *(short8*)(ErB + epos[it]) = ereg[it];

        __syncthreads();   // staging visible

        // ---- QK^T -> S1 (C-layout) ----
        float4v S1[4];
        #pragma unroll
        for (int nt = 0; nt < 4; ++nt) {
            int row = nt * 16 + l16;
            short8 b0 = *(const short8*)(KsB + row * 128 + ((quad ^ xk) << 4));
            short8 b1 = *(const short8*)(KsB + row * 128 + (((quad + 4) ^ xk) << 4));
            float4v a = (float4v){0.f, 0.f, 0.f, 0.f};
            a = __builtin_amdgcn_mfma_f32_16x16x32_bf16(Qa0, b0, a, 0, 0, 0);
            a = __builtin_amdgcn_mfma_f32_16x16x32_bf16(Qa1, b1, a, 0, 0, 0);
            S1[nt] = a;
        }

        // ---- QEr tiles: carry 1, compute 4 fresh (5 at jt==0) ----
        if (jt == 0) { COMP_L(0); } else { L[0] = L[4]; }
        COMP_L(1); COMP_L(2); COMP_L(3); COMP_L(4);

        // ---- Srel extract (bpermute) + softmax + P writes ----
        const bool diag = (jt == ix);
        #pragma unroll
        for (int rg = 0; rg < 4; ++rg) {
            const int usel = quad * 4 + rg;
            const int thr = 15 - usel;
            const int sidx = ((lane & 48) | ((l16 + thr) & 15)) * 4;
            const bool give_lo = (l16 >= thr);
            float sv[4];
            #pragma unroll
            for (int nt = 0; nt < 4; ++nt) {
                float prov = give_lo ? L[nt][rg] : L[nt + 1][rg];
                float qe = __int_as_float(
                    __builtin_amdgcn_ds_bpermute(sidx, __float_as_int(prov)));
                float s = (S1[nt][rg] + qe) * 0.125f;
                if (diag && (nt * 16 + l16 > w * 16 + usel)) s = -1e30f;
                sv[nt] = s;
            }
            float mx = fmaxf(fmaxf(sv[0], sv[1]), fmaxf(sv[2], sv[3]));
            mx = fmaxf(mx, __shfl_xor(mx, 1));
            mx = fmaxf(mx, __shfl_xor(mx, 2));
            mx = fmaxf(mx, __shfl_xor(mx, 4));
            mx = fmaxf(mx, __shfl_xor(mx, 8));
            float mnew = fmaxf(mrow[rg], mx);
            float alpha = __expf(mrow[rg] - mnew);
            mrow[rg] = mnew;
            const int i_ = w * 16 + usel;
            const int ikey = (i_ & 7);
            float sum = 0.f;
            #pragma unroll
            for (int nt = 0; nt < 4; ++nt) {
                float p = __expf(sv[nt] - mnew);
                sum += p;
                int j_ = nt * 16 + l16;
                *(u16t*)(PsB + i_ * 128 + (((j_ >> 3) ^ ikey) << 4) + (j_ & 7) * 2) = f2b(p);
            }
            sum += __shfl_xor(sum, 1);
            sum += __shfl_xor(sum, 2);
            sum += __shfl_xor(sum, 4);
            sum += __shfl_xor(sum, 8);
            lrow[rg] = lrow[rg] * alpha + sum;
            #pragma unroll
            for (int td = 0; td < 4; ++td) accO[td][rg] *= alpha;
        }
        __syncthreads();   // Ps visible

        // ---- PV : O += P @ V ----
        {
            int ar = w * 16 + l16;
            short8 pa0 = *(const short8*)(PsB + ar * 128 + ((quad ^ (ar & 7)) << 4));
            short8 pa1 = *(const short8*)(PsB + ar * 128 + (((quad + 4) ^ (ar & 7)) << 4));
            #pragma unroll
            for (int td = 0; td < 4; ++td) {
                int row = td * 16 + l16;
                short8 b0 = *(const short8*)(VsB + row * 128 + ((quad ^ xk) << 4));
                short8 b1 = *(const short8*)(VsB + row * 128 + (((quad + 4) ^ xk) << 4));
                accO[td] = __builtin_amdgcn_mfma_f32_16x16x32_bf16(pa0, b0, accO[td], 0, 0, 0);
                accO[td] = __builtin_amdgcn_mfma_f32_16x16x32_bf16(pa1, b1, accO[td], 0, 0, 0);
            }
        }
    }
#undef COMP_L

    // ---- epilogue ----
    float* ob = out + (size_t)bb * S * D + (size_t)hh * 64;
    #pragma unroll
    for (int rg = 0; rg < 4; ++rg) {
        int s = s0 + w * 16 + quad * 4 + rg;
        float inv = 1.f / lrow[rg];
        #pragma unroll
        for (int td = 0; td < 4; ++td)
            ob[(size_t)s * D + td * 16 + l16] = accO[td][rg] * inv;
    }
}

extern "C" void kernel_launch(void* const* d_in, const int* in_sizes, int n_in,
                              void* d_out, int out_size, void* d_ws, size_t ws_size,
                              hipStream_t stream) {
    const float* x  = (const float*)d_in[0];
    const float* Wq = (const float*)d_in[1];
    const float* bq = (const float*)d_in[2];
    const float* Wk = (const float*)d_in[3];
    const float* bk = (const float*)d_in[4];
    const float* Wv = (const float*)d_in[5];
    const float* bv = (const float*)d_in[6];
    const float* Er = (const float*)d_in[7];
    float* out = (float*)d_out;

    u16t* ws16 = (u16t*)d_ws;
    u16t* xb  = ws16 + XB_OFF;
    u16t* wqb = ws16 + WQ_OFF;
    u16t* wkb = ws16 + WK_OFF;
    u16t* wvb = ws16 + WV_OFF;
    u16t* erb = ws16 + ER_OFF;
    u16t* qw  = ws16 + QW_OFF;
    u16t* kw  = ws16 + KW_OFF;
    u16t* vTw = ws16 + VT_OFF;

    prep_bf16<<<dim3(7296), dim3(256), 0, stream>>>(x, Wq, Wk, Wv, Er, (u64*)d_ws);

    qkv_mfma<<<dim3(32, 8, 3), dim3(256), 0, stream>>>(
        xb, wqb, wkb, wvb, bq, bk, bv, qw, kw, vTw);

    attn_mfma<<<dim3(32, 32), dim3(256), 0, stream>>>(qw, kw, vTw, erb, out);
}

// Round 6
// 211.609 us; speedup vs baseline: 1.8169x; 1.8169x over previous
//
#include <hip/hip_runtime.h>
#include <hip/hip_bf16.h>

constexpr int B  = 2;
constexpr int S  = 2048;
constexpr int D  = 1024;
constexpr int H  = 16;

typedef unsigned short u16t;
typedef unsigned long long u64;
typedef __attribute__((ext_vector_type(8))) short short8;
typedef __attribute__((ext_vector_type(4))) float float4v;

__device__ __forceinline__ float b2f(u16t u) {
    union { unsigned int i; float f; } c; c.i = ((unsigned int)u) << 16; return c.f;
}
__device__ __forceinline__ u16t f2b(float f) {
    __hip_bfloat16 h = __float2bfloat16(f);
    union { __hip_bfloat16 h; u16t u; } c; c.h = h; return c.u;
}
__device__ __forceinline__ u64 pack4(float4 v) {
    return (u64)f2b(v.x) | ((u64)f2b(v.y) << 16) | ((u64)f2b(v.z) << 32) | ((u64)f2b(v.w) << 48);
}

// ws layout (u16 units)
constexpr size_t XB_OFF = 0;          // x bf16       4194304
constexpr size_t WQ_OFF = 4194304;    // Wq bf16      1048576
constexpr size_t WK_OFF = 5242880;
constexpr size_t WV_OFF = 6291456;
constexpr size_t ER_OFF = 7340032;    // Er bf16       131072
constexpr size_t QW_OFF = 7471104;    // q  bf16 [bh][s][d]
constexpr size_t KW_OFF = 11665408;   // k  bf16 [bh][s][d]
constexpr size_t VT_OFF = 15859712;   // v^T bf16 [bh][d][s]

// ---------------------------------------------------------------------------
// Prep: convert x, Wq, Wk, Wv, Er fp32 -> bf16 into one contiguous ws region.
// ---------------------------------------------------------------------------
__global__ __launch_bounds__(256) void prep_bf16(
    const float* __restrict__ x,  const float* __restrict__ Wq,
    const float* __restrict__ Wk, const float* __restrict__ Wv,
    const float* __restrict__ Er, u64* __restrict__ dst)
{
    size_t i4 = (size_t)blockIdx.x * 256 + threadIdx.x;   // float4 index
    const float* src; size_t off;
    if      (i4 < 1048576) { src = x;  off = i4; }
    else if (i4 < 1310720) { src = Wq; off = i4 - 1048576; }
    else if (i4 < 1572864) { src = Wk; off = i4 - 1310720; }
    else if (i4 < 1835008) { src = Wv; off = i4 - 1572864; }
    else                   { src = Er; off = i4 - 1835008; }
    float4 v = ((const float4*)src)[off];
    dst[i4] = pack4(v);
}

// ---------------------------------------------------------------------------
// QKV projection, bf16 MFMA, BM=BN=128, BK=64.
// q,k -> [bh][s][d] bf16; v -> transposed [bh][d][s] bf16.
// ---------------------------------------------------------------------------
__global__ __launch_bounds__(256, 3) void qkv_mfma(
    const u16t* __restrict__ xb,
    const u16t* __restrict__ wqb, const u16t* __restrict__ wkb, const u16t* __restrict__ wvb,
    const float* __restrict__ bq, const float* __restrict__ bk, const float* __restrict__ bv,
    u16t* __restrict__ qo, u16t* __restrict__ ko, u16t* __restrict__ vT)
{
    const int z = blockIdx.z;
    const u16t*  W    = (z == 0) ? wqb : (z == 1) ? wkb : wvb;
    const float* bias = (z == 0) ? bq  : (z == 1) ? bk  : bv;

    __shared__ __align__(16) u16t Xs[128][72];
    __shared__ __align__(16) u16t Ws[128][72];

    const int tid = threadIdx.x;
    const int w = tid >> 6, lane = tid & 63;
    const int quad = lane >> 4, l16 = lane & 15;
    const int m0 = blockIdx.x * 128, n0 = blockIdx.y * 128;
    const int mi = (w >> 1) * 64, ni = (w & 1) * 64;

    float4v acc[4][4];
    #pragma unroll
    for (int mt = 0; mt < 4; ++mt)
        #pragma unroll
        for (int nt = 0; nt < 4; ++nt) acc[mt][nt] = (float4v){0.f, 0.f, 0.f, 0.f};

    for (int k0 = 0; k0 < D; k0 += 64) {
        short8 xa[4], wa[4];
        #pragma unroll
        for (int it = 0; it < 4; ++it) {
            int idx = tid + it * 256, r = idx >> 3, c = idx & 7;
            xa[it] = *(const short8*)&xb[(size_t)(m0 + r) * D + k0 + c * 8];
            wa[it] = *(const short8*)&W [(size_t)(n0 + r) * D + k0 + c * 8];
        }
        __syncthreads();
        #pragma unroll
        for (int it = 0; it < 4; ++it) {
            int idx = tid + it * 256, r = idx >> 3, c = idx & 7;
            *(short8*)&Xs[r][c * 8] = xa[it];
            *(short8*)&Ws[r][c * 8] = wa[it];
        }
        __syncthreads();
        short8 af[4][2], bf[4][2];
        #pragma unroll
        for (int mt = 0; mt < 4; ++mt) {
            af[mt][0] = *(const short8*)&Xs[mi + mt * 16 + l16][quad * 8];
            af[mt][1] = *(const short8*)&Xs[mi + mt * 16 + l16][quad * 8 + 32];
        }
        #pragma unroll
        for (int nt = 0; nt < 4; ++nt) {
            bf[nt][0] = *(const short8*)&Ws[ni + nt * 16 + l16][quad * 8];
            bf[nt][1] = *(const short8*)&Ws[ni + nt * 16 + l16][quad * 8 + 32];
        }
        #pragma unroll
        for (int mt = 0; mt < 4; ++mt)
            #pragma unroll
            for (int nt = 0; nt < 4; ++nt) {
                acc[mt][nt] = __builtin_amdgcn_mfma_f32_16x16x32_bf16(af[mt][0], bf[nt][0], acc[mt][nt], 0, 0, 0);
                acc[mt][nt] = __builtin_amdgcn_mfma_f32_16x16x32_bf16(af[mt][1], bf[nt][1], acc[mt][nt], 0, 0, 0);
            }
    }

    float bias_v[4];
    #pragma unroll
    for (int nt = 0; nt < 4; ++nt) bias_v[nt] = bias[n0 + ni + nt * 16 + l16];

    #pragma unroll
    for (int mt = 0; mt < 4; ++mt)
        #pragma unroll
        for (int nt = 0; nt < 4; ++nt) {
            int n = n0 + ni + nt * 16 + l16;
            int h = n >> 6, dh = n & 63;
            int mb = m0 + mi + mt * 16 + quad * 4;
            int b_ = mb >> 11, s = mb & (S - 1);
            if (z == 2) {
                float4 o;
                o.x = acc[mt][nt][0] + bias_v[nt];
                o.y = acc[mt][nt][1] + bias_v[nt];
                o.z = acc[mt][nt][2] + bias_v[nt];
                o.w = acc[mt][nt][3] + bias_v[nt];
                *(u64*)&vT[((size_t)(b_ * H + h) * 64 + dh) * S + s] = pack4(o);
            } else {
                u16t* out = (z == 0) ? qo : ko;
                #pragma unroll
                for (int rg = 0; rg < 4; ++rg)
                    out[((size_t)(b_ * H + h) * S + s + rg) * 64 + dh] =
                        f2b(acc[mt][nt][rg] + bias_v[nt]);
            }
        }
}

// ---------------------------------------------------------------------------
// Flash attention + relative position, bf16 MFMA.
// Round 6: static-max softmax (no online max/alpha; p = exp2(s*c - M2),
// row-sum as per-lane register partials reduced once at the end),
// Er B-frags direct from global (no Er LDS), O^T accumulation (vectorized
// epilogue), 2 barriers/iter. LDS = Ks 8K + Vs 8K + Ps 8K + lrows 256B.
// ---------------------------------------------------------------------------
__global__ __launch_bounds__(256, 4) void attn_mfma(
    const u16t* __restrict__ q, const u16t* __restrict__ k,
    const u16t* __restrict__ vT, const u16t* __restrict__ er,
    float* __restrict__ out)
{
    __shared__ __align__(16) u16t KsS[64 * 64];
    __shared__ __align__(16) u16t VsS[64 * 64];
    __shared__ __align__(16) u16t PsS[64 * 64];
    __shared__ float lrows[64];
    char* KsB = (char*)KsS;
    char* VsB = (char*)VsS;
    char* PsB = (char*)PsS;

    const int tid = threadIdx.x;
    const int w = tid >> 6, lane = tid & 63;
    const int quad = lane >> 4, l16 = lane & 15;
    const int bh = blockIdx.x;
    const int ix = (int)gridDim.y - 1 - (int)blockIdx.y;   // longest blocks dispatch first
    const int s0 = ix * 64;
    const int hh = bh & (H - 1), bb = bh >> 4;

    const u16t* qb = q  + (size_t)bh * S * 64;
    const u16t* kb = k  + (size_t)bh * S * 64;
    const u16t* vb = vT + (size_t)bh * 64 * S;

    // Q A-fragments, registers forever
    const size_t qoff = (size_t)(s0 + w * 16 + l16) * 64;
    const short8 Qa0 = *(const short8*)&qb[qoff + quad * 8];
    const short8 Qa1 = *(const short8*)&qb[qoff + 32 + quad * 8];

    float4v accO[4], L[5];
    #pragma unroll
    for (int t = 0; t < 4; ++t) accO[t] = (float4v){0.f, 0.f, 0.f, 0.f};
    float lsum[4] = {0.f, 0.f, 0.f, 0.f};

    const int xk = (l16 & 7);   // swizzle key for frag reads

    // exp2-domain scaling: p = exp2(s_raw * 0.125*log2(e) - M2), M2 = 12*log2(e)
    const float SC = 0.18033688f;
    const float M2 = 17.3125f;

    for (int jt = 0; jt <= ix; ++jt) {
        const int t0 = jt * 64;
        const int jbase = S - 64 - s0 + t0;   // >= 0
        const bool diag = (jt == ix);

        // ---- global loads into registers (no LDS touch yet) ----
        short8 kreg[2], vreg[2];
        int kpos[2];
        #pragma unroll
        for (int it = 0; it < 2; ++it) {
            int idx = tid + it * 256;            // [0,512)
            int r = idx >> 3, c = idx & 7;
            kreg[it] = *(const short8*)&kb[(size_t)(t0 + r) * 64 + c * 8];
            kpos[it] = r * 128 + ((c ^ (r & 7)) << 4);
            vreg[it] = *(const short8*)&vb[(size_t)r * S + t0 + c * 8];
        }
        // Er B-fragments straight from global: tiles c=1..4 (and c=0 at jt==0)
        short8 ef0[4], ef1[4];
        #pragma unroll
        for (int c = 1; c <= 4; ++c) {
            int grow = jbase + (3 - w + c) * 16 + l16;
            if (grow > S - 1) grow = S - 1;
            const u16t* ep = &er[(size_t)grow * 64 + quad * 8];
            ef0[c - 1] = *(const short8*)ep;
            ef1[c - 1] = *(const short8*)(ep + 32);
        }

        __syncthreads();   // all reads of Ks/Vs from prev iter done

        #pragma unroll
        for (int it = 0; it < 2; ++it) {
            *(short8*)(KsB + kpos[it]) = kreg[it];
            *(short8*)(VsB + kpos[it]) = vreg[it];
        }
        __syncthreads();   // staging visible

        // ---- QK^T -> S1 (C-layout) ----
        float4v S1[4];
        #pragma unroll
        for (int nt = 0; nt < 4; ++nt) {
            int row = nt * 16 + l16;
            short8 b0 = *(const short8*)(KsB + row * 128 + ((quad ^ xk) << 4));
            short8 b1 = *(const short8*)(KsB + row * 128 + (((quad + 4) ^ xk) << 4));
            float4v a = (float4v){0.f, 0.f, 0.f, 0.f};
            a = __builtin_amdgcn_mfma_f32_16x16x32_bf16(Qa0, b0, a, 0, 0, 0);
            a = __builtin_amdgcn_mfma_f32_16x16x32_bf16(Qa1, b1, a, 0, 0, 0);
            S1[nt] = a;
        }

        // ---- QEr tiles: carry 1, compute 4 fresh (5 at jt==0) ----
        if (jt == 0) {
            int grow = jbase + (3 - w) * 16 + l16;
            if (grow > S - 1) grow = S - 1;
            const u16t* ep = &er[(size_t)grow * 64 + quad * 8];
            short8 e0 = *(const short8*)ep;
            short8 e1 = *(const short8*)(ep + 32);
            float4v e = (float4v){0.f, 0.f, 0.f, 0.f};
            e = __builtin_amdgcn_mfma_f32_16x16x32_bf16(Qa0, e0, e, 0, 0, 0);
            e = __builtin_amdgcn_mfma_f32_16x16x32_bf16(Qa1, e1, e, 0, 0, 0);
            L[0] = e;
        } else {
            L[0] = L[4];
        }
        #pragma unroll
        for (int c = 1; c <= 4; ++c) {
            float4v e = (float4v){0.f, 0.f, 0.f, 0.f};
            e = __builtin_amdgcn_mfma_f32_16x16x32_bf16(Qa0, ef0[c - 1], e, 0, 0, 0);
            e = __builtin_amdgcn_mfma_f32_16x16x32_bf16(Qa1, ef1[c - 1], e, 0, 0, 0);
            L[c] = e;
        }

        // ---- Srel extract (bpermute) + static-max softmax + P writes ----
        #pragma unroll
        for (int rg = 0; rg < 4; ++rg) {
            const int usel = quad * 4 + rg;
            const int thr = 15 - usel;
            const int sidx = ((lane & 48) | ((l16 + thr) & 15)) * 4;
            const bool give_lo = (l16 >= thr);
            const int i_ = w * 16 + usel;
            const int ikey = i_ & 7;
            float psum = 0.f;
            #pragma unroll
            for (int nt = 0; nt < 4; ++nt) {
                float prov = give_lo ? L[nt][rg] : L[nt + 1][rg];
                float qe = __int_as_float(
                    __builtin_amdgcn_ds_bpermute(sidx, __float_as_int(prov)));
                float s2 = fmaf(S1[nt][rg] + qe, SC, -M2);
                float p = (diag && (nt * 16 + l16 > i_ - w * 16 + w * 16) && (nt * 16 + l16 > w * 16 + usel))
                              ? 0.f : exp2f(s2);
                p = (diag && (nt * 16 + l16 > w * 16 + usel)) ? 0.f : p;
                psum += p;
                int j_ = nt * 16 + l16;
                *(u16t*)(PsB + i_ * 128 + (((j_ >> 3) ^ ikey) << 4) + (j_ & 7) * 2) = f2b(p);
            }
            lsum[rg] += psum;
        }
        // (Ps rows are wave-private; DS pipe is in-order per wave: no barrier)

        // ---- PV, O^T form: accO = V^T(A) x P(B) ----
        {
            int ar = w * 16 + l16;
            short8 pa0 = *(const short8*)(PsB + ar * 128 + ((quad ^ (ar & 7)) << 4));
            short8 pa1 = *(const short8*)(PsB + ar * 128 + (((quad + 4) ^ (ar & 7)) << 4));
            #pragma unroll
            for (int td = 0; td < 4; ++td) {
                int row = td * 16 + l16;
                short8 a0 = *(const short8*)(VsB + row * 128 + ((quad ^ xk) << 4));
                short8 a1 = *(const short8*)(VsB + row * 128 + (((quad + 4) ^ xk) << 4));
                accO[td] = __builtin_amdgcn_mfma_f32_16x16x32_bf16(a0, pa0, accO[td], 0, 0, 0);
                accO[td] = __builtin_amdgcn_mfma_f32_16x16x32_bf16(a1, pa1, accO[td], 0, 0, 0);
            }
        }
    }

    // ---- final row-sum reduce (once, not per-iter) ----
    #pragma unroll
    for (int rg = 0; rg < 4; ++rg) {
        float s = lsum[rg];
        s += __shfl_xor(s, 1);
        s += __shfl_xor(s, 2);
        s += __shfl_xor(s, 4);
        s += __shfl_xor(s, 8);
        if (l16 == 0) lrows[w * 16 + quad * 4 + rg] = s;
    }
    // wave-private region, same-wave DS ordering
    float inv = 1.f / lrows[w * 16 + l16];

    // ---- epilogue: lane owns q-row s0 + w*16 + l16, all 64 d ----
    float* ob = out + (size_t)bb * S * D + (size_t)hh * 64
                + (size_t)(s0 + w * 16 + l16) * D;
    #pragma unroll
    for (int td = 0; td < 4; ++td) {
        float4 o;
        o.x = accO[td][0] * inv;
        o.y = accO[td][1] * inv;
        o.z = accO[td][2] * inv;
        o.w = accO[td][3] * inv;
        *(float4*)&ob[td * 16 + quad * 4] = o;
    }
}

extern "C" void kernel_launch(void* const* d_in, const int* in_sizes, int n_in,
                              void* d_out, int out_size, void* d_ws, size_t ws_size,
                              hipStream_t stream) {
    const float* x  = (const float*)d_in[0];
    const float* Wq = (const float*)d_in[1];
    const float* bq = (const float*)d_in[2];
    const float* Wk = (const float*)d_in[3];
    const float* bk = (const float*)d_in[4];
    const float* Wv = (const float*)d_in[5];
    const float* bv = (const float*)d_in[6];
    const float* Er = (const float*)d_in[7];
    float* out = (float*)d_out;

    u16t* ws16 = (u16t*)d_ws;
    u16t* xb  = ws16 + XB_OFF;
    u16t* wqb = ws16 + WQ_OFF;
    u16t* wkb = ws16 + WK_OFF;
    u16t* wvb = ws16 + WV_OFF;
    u16t* erb = ws16 + ER_OFF;
    u16t* qw  = ws16 + QW_OFF;
    u16t* kw  = ws16 + KW_OFF;
    u16t* vTw = ws16 + VT_OFF;

    prep_bf16<<<dim3(7296), dim3(256), 0, stream>>>(x, Wq, Wk, Wv, Er, (u64*)d_ws);

    qkv_mfma<<<dim3(32, 8, 3), dim3(256), 0, stream>>>(
        xb, wqb, wkb, wvb, bq, bk, bv, qw, kw, vTw);

    attn_mfma<<<dim3(32, 32), dim3(256), 0, stream>>>(qw, kw, vTw, erb, out);
}

// Round 7
// 202.808 us; speedup vs baseline: 1.8958x; 1.0434x over previous
//
#include <hip/hip_runtime.h>
#include <hip/hip_bf16.h>

constexpr int B  = 2;
constexpr int S  = 2048;
constexpr int D  = 1024;
constexpr int H  = 16;

typedef unsigned short u16t;
typedef unsigned long long u64;
typedef __attribute__((ext_vector_type(8))) short short8;
typedef __attribute__((ext_vector_type(4))) float float4v;

__device__ __forceinline__ float b2f(unsigned int u) {
    union { unsigned int i; float f; } c; c.i = u << 16; return c.f;
}
__device__ __forceinline__ u16t f2b(float f) {
    __hip_bfloat16 h = __float2bfloat16(f);
    union { __hip_bfloat16 h; u16t u; } c; c.h = h; return c.u;
}
__device__ __forceinline__ unsigned int pkbf(float a, float b) {
    return (unsigned int)f2b(a) | ((unsigned int)f2b(b) << 16);
}
__device__ __forceinline__ u64 pack4(float4 v) {
    return (u64)f2b(v.x) | ((u64)f2b(v.y) << 16) | ((u64)f2b(v.z) << 32) | ((u64)f2b(v.w) << 48);
}

typedef __attribute__((address_space(1))) const unsigned int* as1_u32p;
typedef __attribute__((address_space(3))) unsigned int* as3_u32p;
__device__ __forceinline__ void gll16(const void* g, void* l) {
    // global -> LDS direct, 16 B/lane, dest = wave-uniform base + lane*16
    __builtin_amdgcn_global_load_lds((as1_u32p)g, (as3_u32p)l, 16, 0, 0);
}

// ws layout (u16 units)
constexpr size_t XB_OFF = 0;          // x bf16       4194304
constexpr size_t WQ_OFF = 4194304;    // Wq bf16      1048576
constexpr size_t WK_OFF = 5242880;
constexpr size_t WV_OFF = 6291456;
constexpr size_t ER_OFF = 7340032;    // Er bf16       131072
constexpr size_t QW_OFF = 7471104;    // q  bf16 [bh][s][d]
constexpr size_t KW_OFF = 11665408;   // k  bf16 [bh][s][d]
constexpr size_t VT_OFF = 15859712;   // v^T bf16 [bh][d][s]

// ---------------------------------------------------------------------------
// Prep: convert x, Wq, Wk, Wv, Er fp32 -> bf16 into one contiguous ws region.
// ---------------------------------------------------------------------------
__global__ __launch_bounds__(256) void prep_bf16(
    const float* __restrict__ x,  const float* __restrict__ Wq,
    const float* __restrict__ Wk, const float* __restrict__ Wv,
    const float* __restrict__ Er, u64* __restrict__ dst)
{
    size_t i4 = (size_t)blockIdx.x * 256 + threadIdx.x;   // float4 index
    const float* src; size_t off;
    if      (i4 < 1048576) { src = x;  off = i4; }
    else if (i4 < 1310720) { src = Wq; off = i4 - 1048576; }
    else if (i4 < 1572864) { src = Wk; off = i4 - 1310720; }
    else if (i4 < 1835008) { src = Wv; off = i4 - 1572864; }
    else                   { src = Er; off = i4 - 1835008; }
    float4 v = ((const float4*)src)[off];
    dst[i4] = pack4(v);
}

// ---------------------------------------------------------------------------
// QKV projection, bf16 MFMA, BM=BN=128, BK=64, software-pipelined staging:
// global loads for k0+64 issue right after the staging barrier so HBM latency
// overlaps the 32 MFMAs of iteration k0.
// q,k -> [bh][s][d] bf16; v -> transposed [bh][d][s] bf16.
// ---------------------------------------------------------------------------
__global__ __launch_bounds__(256, 3) void qkv_mfma(
    const u16t* __restrict__ xb,
    const u16t* __restrict__ wqb, const u16t* __restrict__ wkb, const u16t* __restrict__ wvb,
    const float* __restrict__ bq, const float* __restrict__ bk, const float* __restrict__ bv,
    u16t* __restrict__ qo, u16t* __restrict__ ko, u16t* __restrict__ vT)
{
    const int z = blockIdx.z;
    const u16t*  W    = (z == 0) ? wqb : (z == 1) ? wkb : wvb;
    const float* bias = (z == 0) ? bq  : (z == 1) ? bk  : bv;

    __shared__ __align__(16) u16t Xs[128][72];
    __shared__ __align__(16) u16t Ws[128][72];

    const int tid = threadIdx.x;
    const int w = tid >> 6, lane = tid & 63;
    const int quad = lane >> 4, l16 = lane & 15;
    const int m0 = blockIdx.x * 128, n0 = blockIdx.y * 128;
    const int mi = (w >> 1) * 64, ni = (w & 1) * 64;

    float4v acc[4][4];
    #pragma unroll
    for (int mt = 0; mt < 4; ++mt)
        #pragma unroll
        for (int nt = 0; nt < 4; ++nt) acc[mt][nt] = (float4v){0.f, 0.f, 0.f, 0.f};

    // preload k0 = 0
    short8 xa[4], wa[4];
    #pragma unroll
    for (int it = 0; it < 4; ++it) {
        int idx = tid + it * 256, r = idx >> 3, c = idx & 7;
        xa[it] = *(const short8*)&xb[(size_t)(m0 + r) * D + c * 8];
        wa[it] = *(const short8*)&W [(size_t)(n0 + r) * D + c * 8];
    }

    for (int k0 = 0; k0 < D; k0 += 64) {
        __syncthreads();
        #pragma unroll
        for (int it = 0; it < 4; ++it) {
            int idx = tid + it * 256, r = idx >> 3, c = idx & 7;
            *(short8*)&Xs[r][c * 8] = xa[it];
            *(short8*)&Ws[r][c * 8] = wa[it];
        }
        __syncthreads();
        if (k0 + 64 < D) {
            #pragma unroll
            for (int it = 0; it < 4; ++it) {
                int idx = tid + it * 256, r = idx >> 3, c = idx & 7;
                xa[it] = *(const short8*)&xb[(size_t)(m0 + r) * D + k0 + 64 + c * 8];
                wa[it] = *(const short8*)&W [(size_t)(n0 + r) * D + k0 + 64 + c * 8];
            }
        }
        short8 af[4][2], bf[4][2];
        #pragma unroll
        for (int mt = 0; mt < 4; ++mt) {
            af[mt][0] = *(const short8*)&Xs[mi + mt * 16 + l16][quad * 8];
            af[mt][1] = *(const short8*)&Xs[mi + mt * 16 + l16][quad * 8 + 32];
        }
        #pragma unroll
        for (int nt = 0; nt < 4; ++nt) {
            bf[nt][0] = *(const short8*)&Ws[ni + nt * 16 + l16][quad * 8];
            bf[nt][1] = *(const short8*)&Ws[ni + nt * 16 + l16][quad * 8 + 32];
        }
        #pragma unroll
        for (int mt = 0; mt < 4; ++mt)
            #pragma unroll
            for (int nt = 0; nt < 4; ++nt) {
                acc[mt][nt] = __builtin_amdgcn_mfma_f32_16x16x32_bf16(af[mt][0], bf[nt][0], acc[mt][nt], 0, 0, 0);
                acc[mt][nt] = __builtin_amdgcn_mfma_f32_16x16x32_bf16(af[mt][1], bf[nt][1], acc[mt][nt], 0, 0, 0);
            }
    }

    float bias_v[4];
    #pragma unroll
    for (int nt = 0; nt < 4; ++nt) bias_v[nt] = bias[n0 + ni + nt * 16 + l16];

    #pragma unroll
    for (int mt = 0; mt < 4; ++mt)
        #pragma unroll
        for (int nt = 0; nt < 4; ++nt) {
            int n = n0 + ni + nt * 16 + l16;
            int h = n >> 6, dh = n & 63;
            int mb = m0 + mi + mt * 16 + quad * 4;
            int b_ = mb >> 11, s = mb & (S - 1);
            if (z == 2) {
                float4 o;
                o.x = acc[mt][nt][0] + bias_v[nt];
                o.y = acc[mt][nt][1] + bias_v[nt];
                o.z = acc[mt][nt][2] + bias_v[nt];
                o.w = acc[mt][nt][3] + bias_v[nt];
                *(u64*)&vT[((size_t)(b_ * H + h) * 64 + dh) * S + s] = pack4(o);
            } else {
                u16t* out = (z == 0) ? qo : ko;
                #pragma unroll
                for (int rg = 0; rg < 4; ++rg)
                    out[((size_t)(b_ * H + h) * S + s + rg) * 64 + dh] =
                        f2b(acc[mt][nt][rg] + bias_v[nt]);
            }
        }
}

// ---------------------------------------------------------------------------
// Flash attention + relative position, bf16 MFMA.
// Round 7: paired q-tiles (ix, 31-ix) -> every block exactly 33 iters
// (perfect CU load balance); K/V double-buffered via global_load_lds width-16
// with ONE end-of-iter barrier (vmcnt drained by __syncthreads = m97 pattern);
// bpermute Srel halved by bf16 pair packing.
// LDS: Ks 16K(dbuf) + Vs 16K(dbuf) + Ps 8K + lrows = 40.25 KB.
// ---------------------------------------------------------------------------
__global__ __launch_bounds__(256, 4) void attn_mfma(
    const u16t* __restrict__ q, const u16t* __restrict__ k,
    const u16t* __restrict__ vT, const u16t* __restrict__ er,
    float* __restrict__ out)
{
    __shared__ __align__(16) u16t KsS[2][64 * 64];
    __shared__ __align__(16) u16t VsS[2][64 * 64];
    __shared__ __align__(16) u16t PsS[64 * 64];
    __shared__ float lrows[64];
    char* KsB = (char*)KsS;
    char* VsB = (char*)VsS;
    char* PsB = (char*)PsS;

    const int tid = threadIdx.x;
    const int w = tid >> 6, lane = tid & 63;
    const int quad = lane >> 4, l16 = lane & 15;
    const int bh = blockIdx.x;
    const int pr = blockIdx.y;            // 0..15 -> pair (pr, 31-pr)
    const int hh = bh & (H - 1), bb = bh >> 4;

    const u16t* qb = q  + (size_t)bh * S * 64;
    const u16t* kb = k  + (size_t)bh * S * 64;
    const u16t* vb = vT + (size_t)bh * 64 * S;

    const int xk = (l16 & 7);             // swizzle key for frag reads
    const float SC = 0.18033688f;         // 0.125 * log2(e)
    const float M2 = 17.3125f;            // static softmax shift (exp2 domain)

    // per-lane staging geometry (chunk ci covers rows ci*8..ci*8+7)
    const int srow = lane >> 3;           // row within chunk
    const int d8s  = (lane & 7) ^ (srow & 7);

    #pragma unroll 1
    for (int ph = 0; ph < 2; ++ph) {
        const int ix = ph ? (31 - pr) : pr;
        const int s0 = ix * 64;

        const size_t qoff = (size_t)(s0 + w * 16 + l16) * 64;
        const short8 Qa0 = *(const short8*)&qb[qoff + quad * 8];
        const short8 Qa1 = *(const short8*)&qb[qoff + 32 + quad * 8];

        float4v accO[4], L[5];
        #pragma unroll
        for (int t = 0; t < 4; ++t) accO[t] = (float4v){0.f, 0.f, 0.f, 0.f};
        float lsum[4] = {0.f, 0.f, 0.f, 0.f};

        // ---- preload tile 0 into buffer 0 ----
        #pragma unroll
        for (int it = 0; it < 2; ++it) {
            int ci = w * 2 + it;
            int prow = ci * 8 + srow;
            gll16(&kb[(size_t)prow * 64 + d8s * 8], KsB + ci * 1024);
            gll16(&vb[(size_t)prow * S + d8s * 8], VsB + ci * 1024);
        }
        __syncthreads();   // drains vmcnt -> tile 0 visible

        for (int jt = 0; jt <= ix; ++jt) {
            const int t0 = jt * 64;
            const int jbase = S - 64 - s0 + t0;   // >= 0
            const bool diag = (jt == ix);
            const int bsel = (jt & 1) * 8192;

            // ---- Er fragment loads (oldest VMEM this iter) ----
            short8 ef0[4], ef1[4], e00, e01;
            #pragma unroll
            for (int c = 1; c <= 4; ++c) {
                int grow = jbase + (3 - w + c) * 16 + l16;
                if (grow > S - 1) grow = S - 1;
                const u16t* ep = &er[(size_t)grow * 64 + quad * 8];
                ef0[c - 1] = *(const short8*)ep;
                ef1[c - 1] = *(const short8*)(ep + 32);
            }
            if (jt == 0) {
                int grow = jbase + (3 - w) * 16 + l16;
                if (grow > S - 1) grow = S - 1;
                const u16t* ep = &er[(size_t)grow * 64 + quad * 8];
                e00 = *(const short8*)ep;
                e01 = *(const short8*)(ep + 32);
            }

            // ---- prefetch next K/V tile into other buffer ----
            if (jt < ix) {
                int nb = ((jt + 1) & 1) * 8192;
                #pragma unroll
                for (int it = 0; it < 2; ++it) {
                    int ci = w * 2 + it;
                    int prow = ci * 8 + srow;
                    gll16(&kb[(size_t)(t0 + 64 + prow) * 64 + d8s * 8], KsB + nb + ci * 1024);
                    gll16(&vb[(size_t)prow * S + t0 + 64 + d8s * 8], VsB + nb + ci * 1024);
                }
            }

            // ---- QK^T -> S1 (C-layout) ----
            float4v S1[4];
            #pragma unroll
            for (int nt = 0; nt < 4; ++nt) {
                int row = nt * 16 + l16;
                short8 b0 = *(const short8*)(KsB + bsel + row * 128 + ((quad ^ xk) << 4));
                short8 b1 = *(const short8*)(KsB + bsel + row * 128 + (((quad + 4) ^ xk) << 4));
                float4v a = (float4v){0.f, 0.f, 0.f, 0.f};
                a = __builtin_amdgcn_mfma_f32_16x16x32_bf16(Qa0, b0, a, 0, 0, 0);
                a = __builtin_amdgcn_mfma_f32_16x16x32_bf16(Qa1, b1, a, 0, 0, 0);
                S1[nt] = a;
            }

            // ---- QEr tiles: carry 1, compute 4 fresh (5 at jt==0) ----
            if (jt == 0) {
                float4v e = (float4v){0.f, 0.f, 0.f, 0.f};
                e = __builtin_amdgcn_mfma_f32_16x16x32_bf16(Qa0, e00, e, 0, 0, 0);
                e = __builtin_amdgcn_mfma_f32_16x16x32_bf16(Qa1, e01, e, 0, 0, 0);
                L[0] = e;
            } else {
                L[0] = L[4];
            }
            #pragma unroll
            for (int c = 1; c <= 4; ++c) {
                float4v e = (float4v){0.f, 0.f, 0.f, 0.f};
                e = __builtin_amdgcn_mfma_f32_16x16x32_bf16(Qa0, ef0[c - 1], e, 0, 0, 0);
                e = __builtin_amdgcn_mfma_f32_16x16x32_bf16(Qa1, ef1[c - 1], e, 0, 0, 0);
                L[c] = e;
            }

            // ---- Srel extract (packed bpermute) + static-max softmax ----
            #pragma unroll
            for (int rg = 0; rg < 4; ++rg) {
                const int usel = quad * 4 + rg;
                const int thr = 15 - usel;
                const int sidx = ((lane & 48) | ((l16 + thr) & 15)) * 4;
                const bool give_lo = (l16 >= thr);
                unsigned int p01 = give_lo ? pkbf(L[0][rg], L[1][rg]) : pkbf(L[1][rg], L[2][rg]);
                unsigned int p23 = give_lo ? pkbf(L[2][rg], L[3][rg]) : pkbf(L[3][rg], L[4][rg]);
                unsigned int q01 = (unsigned int)__builtin_amdgcn_ds_bpermute(sidx, (int)p01);
                unsigned int q23 = (unsigned int)__builtin_amdgcn_ds_bpermute(sidx, (int)p23);
                float qe[4] = { b2f(q01 & 0xffffu), b2f(q01 >> 16),
                                b2f(q23 & 0xffffu), b2f(q23 >> 16) };
                const int i_ = w * 16 + usel;
                const int ikey = i_ & 7;
                float psum = 0.f;
                #pragma unroll
                for (int nt = 0; nt < 4; ++nt) {
                    float s2 = fmaf(S1[nt][rg] + qe[nt], SC, -M2);
                    float p = (diag && (nt * 16 + l16 > i_)) ? 0.f : exp2f(s2);
                    psum += p;
                    int j_ = nt * 16 + l16;
                    *(u16t*)(PsB + i_ * 128 + (((j_ >> 3) ^ ikey) << 4) + (j_ & 7) * 2) = f2b(p);
                }
                lsum[rg] += psum;
            }
            // (Ps rows wave-private; same-wave DS ordering -> no barrier)

            // ---- PV, O^T form: accO = V^T(A) x P(B) ----
            {
                int ar = w * 16 + l16;
                short8 pa0 = *(const short8*)(PsB + ar * 128 + ((quad ^ (ar & 7)) << 4));
                short8 pa1 = *(const short8*)(PsB + ar * 128 + (((quad + 4) ^ (ar & 7)) << 4));
                #pragma unroll
                for (int td = 0; td < 4; ++td) {
                    int row = td * 16 + l16;
                    short8 a0 = *(const short8*)(VsB + bsel + row * 128 + ((quad ^ xk) << 4));
                    short8 a1 = *(const short8*)(VsB + bsel + row * 128 + (((quad + 4) ^ xk) << 4));
                    accO[td] = __builtin_amdgcn_mfma_f32_16x16x32_bf16(a0, pa0, accO[td], 0, 0, 0);
                    accO[td] = __builtin_amdgcn_mfma_f32_16x16x32_bf16(a1, pa1, accO[td], 0, 0, 0);
                }
            }
            __syncthreads();   // prev-buffer reads done + prefetch drained
        }

        // ---- final row-sum reduce (once per phase) ----
        #pragma unroll
        for (int rg = 0; rg < 4; ++rg) {
            float s = lsum[rg];
            s += __shfl_xor(s, 1);
            s += __shfl_xor(s, 2);
            s += __shfl_xor(s, 4);
            s += __shfl_xor(s, 8);
            if (l16 == 0) lrows[w * 16 + quad * 4 + rg] = s;
        }
        float inv = 1.f / lrows[w * 16 + l16];

        // ---- epilogue: lane owns q-row s0 + w*16 + l16, all 64 d ----
        float* ob = out + (size_t)bb * S * D + (size_t)hh * 64
                    + (size_t)(s0 + w * 16 + l16) * D;
        #pragma unroll
        for (int td = 0; td < 4; ++td) {
            float4 o;
            o.x = accO[td][0] * inv;
            o.y = accO[td][1] * inv;
            o.z = accO[td][2] * inv;
            o.w = accO[td][3] * inv;
            *(float4*)&ob[td * 16 + quad * 4] = o;
        }
    }
}

extern "C" void kernel_launch(void* const* d_in, const int* in_sizes, int n_in,
                              void* d_out, int out_size, void* d_ws, size_t ws_size,
                              hipStream_t stream) {
    const float* x  = (const float*)d_in[0];
    const float* Wq = (const float*)d_in[1];
    const float* bq = (const float*)d_in[2];
    const float* Wk = (const float*)d_in[3];
    const float* bk = (const float*)d_in[4];
    const float* Wv = (const float*)d_in[5];
    const float* bv = (const float*)d_in[6];
    const float* Er = (const float*)d_in[7];
    float* out = (float*)d_out;

    u16t* ws16 = (u16t*)d_ws;
    u16t* xb  = ws16 + XB_OFF;
    u16t* wqb = ws16 + WQ_OFF;
    u16t* wkb = ws16 + WK_OFF;
    u16t* wvb = ws16 + WV_OFF;
    u16t* erb = ws16 + ER_OFF;
    u16t* qw  = ws16 + QW_OFF;
    u16t* kw  = ws16 + KW_OFF;
    u16t* vTw = ws16 + VT_OFF;

    prep_bf16<<<dim3(7296), dim3(256), 0, stream>>>(x, Wq, Wk, Wv, Er, (u64*)d_ws);

    qkv_mfma<<<dim3(32, 8, 3), dim3(256), 0, stream>>>(
        xb, wqb, wkb, wvb, bq, bk, bv, qw, kw, vTw);

    attn_mfma<<<dim3(32, 16), dim3(256), 0, stream>>>(qw, kw, vTw, erb, out);
}